// Round 7
// baseline (183.256 us; speedup 1.0000x reference)
//
#include <hip/hip_runtime.h>
#include <math.h>
#include <stdint.h>

// Single-head GAT layer, MI355X (gfx950). 6 kernels:
//   k_count : per-block LDS histogram over coarse buckets (dst>>6); zeroes cursor
//   k_bsum  : per-bucket totals across blocks + order-free base alloc
//             (wave shfl-scan + one atomicAdd per wave)  [replaces scan1]
//   k_bin   : re-read edges, LDS cursors -> packed (dst<<16|src) per bucket
//   k_wconv : W f32[256][64] -> f16 B-fragment-ordered Wf (32KB)
//   k_gemmf16: z = X@W via mfma_f32_16x16x32_f16, fused el/er; z stored f16
//   k_fagg  : per bucket: stage edges->LDS, fine 64-bin CSR in LDS, then
//             per-dst-wave online softmax + weighted gather of z  [fine+agg fused]

constexpr int IN_D   = 256;
constexpr int OUT_D  = 64;
constexpr int NBLK   = 256;    // binning blocks
constexpr int NBMAX  = 1024;   // max coarse buckets (n <= 65536)
constexpr int CAPE   = 4096;   // max edges per coarse bucket (mean ~1024, 4x headroom)

typedef _Float16 f16x8 __attribute__((ext_vector_type(8)));
typedef float    f32x4 __attribute__((ext_vector_type(4)));

__device__ __forceinline__ void gload_lds16(const void* g, void* l) {
    __builtin_amdgcn_global_load_lds(
        (const __attribute__((address_space(1))) uint32_t*)g,
        (__attribute__((address_space(3))) uint32_t*)l, 16, 0, 0);
}

// ---- build phase ----

__global__ __launch_bounds__(256) void k_count(const int* __restrict__ dst,
                                               int* __restrict__ blkcnt,
                                               int* __restrict__ cursor,
                                               int E, int nb, int chunk) {
    __shared__ int cnt[NBMAX];
    const int b = blockIdx.x, tid = threadIdx.x;
    if (b == 0 && tid == 0) *cursor = 0;
    for (int i = tid; i < nb; i += 256) cnt[i] = 0;
    __syncthreads();
    const int lo = b * chunk;
    const int hi = (lo + chunk < E) ? lo + chunk : E;
    const int nv = (hi - lo) & ~3;
    for (int e = lo + tid * 4; e < lo + nv; e += 1024) {
        int4 d4 = *(const int4*)&dst[e];
        atomicAdd(&cnt[d4.x >> 6], 1);
        atomicAdd(&cnt[d4.y >> 6], 1);
        atomicAdd(&cnt[d4.z >> 6], 1);
        atomicAdd(&cnt[d4.w >> 6], 1);
    }
    for (int e = lo + nv + tid; e < hi; e += 256) atomicAdd(&cnt[dst[e] >> 6], 1);
    __syncthreads();
    for (int i = tid; i < nb; i += 256) blkcnt[(size_t)b * NBMAX + i] = cnt[i];
}

// Per-bucket prefix over blocks + contiguous base allocation (order-free).
__global__ __launch_bounds__(256) void k_bsum(int* __restrict__ blkcnt,
                                              int* __restrict__ total,
                                              int* __restrict__ bbase,
                                              int* __restrict__ cursor, int nb) {
    const int j = blockIdx.x * 256 + threadIdx.x;
    const int lane = threadIdx.x & 63;
    int run = 0;
    if (j < nb) {
        #pragma unroll 8
        for (int b = 0; b < NBLK; ++b) {
            int v = blkcnt[(size_t)b * NBMAX + j];
            blkcnt[(size_t)b * NBMAX + j] = run;   // prefix of blocks < b
            run += v;
        }
    }
    int incl = run;
    #pragma unroll
    for (int ofs = 1; ofs < 64; ofs <<= 1) {
        int u = __shfl_up(incl, ofs, 64);
        if (lane >= ofs) incl += u;
    }
    int base = 0;
    if (lane == 63) base = atomicAdd(cursor, incl);   // wave total
    base = __shfl(base, 63, 64);
    if (j < nb) { total[j] = run; bbase[j] = base + incl - run; }
}

__global__ __launch_bounds__(256) void k_bin(const int* __restrict__ dst,
                                             const int* __restrict__ src,
                                             const int* __restrict__ blkcnt,
                                             const int* __restrict__ bbase,
                                             uint32_t* __restrict__ binned,
                                             int E, int nb, int chunk) {
    __shared__ int cur[NBMAX];
    const int b = blockIdx.x, tid = threadIdx.x;
    for (int i = tid; i < nb; i += 256)
        cur[i] = bbase[i] + blkcnt[(size_t)b * NBMAX + i];
    __syncthreads();
    const int lo = b * chunk;
    const int hi = (lo + chunk < E) ? lo + chunk : E;
    const int nv = (hi - lo) & ~3;
    for (int e = lo + tid * 4; e < lo + nv; e += 1024) {
        int4 d4 = *(const int4*)&dst[e];
        int4 s4 = *(const int4*)&src[e];
        int p;
        p = atomicAdd(&cur[d4.x >> 6], 1); binned[p] = ((uint32_t)d4.x << 16) | (uint32_t)s4.x;
        p = atomicAdd(&cur[d4.y >> 6], 1); binned[p] = ((uint32_t)d4.y << 16) | (uint32_t)s4.y;
        p = atomicAdd(&cur[d4.z >> 6], 1); binned[p] = ((uint32_t)d4.z << 16) | (uint32_t)s4.z;
        p = atomicAdd(&cur[d4.w >> 6], 1); binned[p] = ((uint32_t)d4.w << 16) | (uint32_t)s4.w;
    }
    for (int e = lo + nv + tid; e < hi; e += 256) {
        const uint32_t d = (uint32_t)dst[e];
        const int pos = atomicAdd(&cur[d >> 6], 1);
        binned[pos] = (d << 16) | (uint32_t)src[e];
    }
}

// ---- math phase ----

// Wf[t], t = ((kc*4+ct)*64+lane)*8+j  holds W[kc*32+(lane>>4)*8+j][ct*16+(lane&15)]
__global__ void k_wconv(const float* __restrict__ W, _Float16* __restrict__ Wf) {
    int t = blockIdx.x * 256 + threadIdx.x;          // 16384 total
    int j    = t & 7;
    int lane = (t >> 3) & 63;
    int ct   = (t >> 9) & 3;
    int kc   = t >> 11;
    int k = kc * 32 + (lane >> 4) * 8 + j;
    int c = ct * 16 + (lane & 15);
    Wf[t] = (_Float16)W[k * OUT_D + c];
}

// Block: 256 thr / 4 waves; wave: 16 rows x 64 cols, K=256 in 8 chunks.
// C/D layout (m89): col = lane&15, row = (lane>>4)*4 + reg.
__global__ __launch_bounds__(256) void k_gemmf16(
        const float* __restrict__ feat, const _Float16* __restrict__ Wf,
        const float* __restrict__ a,
        _Float16* __restrict__ z, float* __restrict__ el, float* __restrict__ er,
        int n)
{
    __shared__ __align__(16) _Float16 WfL[IN_D * OUT_D];   // 32 KB, frag order

    const int tid  = threadIdx.x;
    const int lane = tid & 63;
    const int wv   = tid >> 6;
    const int row0 = blockIdx.x * 64 + wv * 16;
    const int kg   = lane >> 4;

    int gr = row0 + (lane & 15); if (gr > n - 1) gr = n - 1;
    const float* frow = feat + (size_t)gr * IN_D;
    float4 r0[8], r1[8];
    #pragma unroll
    for (int kc = 0; kc < 8; ++kc) {
        const float4* fp = (const float4*)(frow + kc * 32 + kg * 8);
        r0[kc] = fp[0];
        r1[kc] = fp[1];
    }

    #pragma unroll
    for (int i = 0; i < 8; ++i) {
        const char* gsrc = (const char*)Wf + (size_t)(i * 256 + tid) * 16;
        char* ldst = (char*)WfL + (size_t)(i * 256 + wv * 64) * 16;
        gload_lds16(gsrc, ldst);
    }
    __syncthreads();

    f32x4 acc[4];
    #pragma unroll
    for (int ct = 0; ct < 4; ++ct) acc[ct] = (f32x4){0.f, 0.f, 0.f, 0.f};

    #pragma unroll
    for (int kc = 0; kc < 8; ++kc) {
        f16x8 af;
        af[0] = (_Float16)r0[kc].x; af[1] = (_Float16)r0[kc].y;
        af[2] = (_Float16)r0[kc].z; af[3] = (_Float16)r0[kc].w;
        af[4] = (_Float16)r1[kc].x; af[5] = (_Float16)r1[kc].y;
        af[6] = (_Float16)r1[kc].z; af[7] = (_Float16)r1[kc].w;
        #pragma unroll
        for (int ct = 0; ct < 4; ++ct) {
            f16x8 bf = *(const f16x8*)&WfL[((kc * 4 + ct) * 64 + lane) * 8];
            acc[ct] = __builtin_amdgcn_mfma_f32_16x16x32_f16(af, bf, acc[ct], 0, 0, 0);
        }
    }

    const int col = lane & 15;
    float av[4], bv[4];
    #pragma unroll
    for (int ct = 0; ct < 4; ++ct) {
        av[ct] = a[ct * 16 + col];
        bv[ct] = a[OUT_D + ct * 16 + col];
    }
    #pragma unroll
    for (int i = 0; i < 4; ++i) {
        const int r = row0 + (lane >> 4) * 4 + i;
        float vl = 0.f, vr = 0.f;
        #pragma unroll
        for (int ct = 0; ct < 4; ++ct) {
            float zv = acc[ct][i];
            if (r < n) z[(size_t)r * OUT_D + ct * 16 + col] = (_Float16)zv;
            vl = fmaf(zv, av[ct], vl);
            vr = fmaf(zv, bv[ct], vr);
        }
        #pragma unroll
        for (int msk = 8; msk >= 1; msk >>= 1) {
            vl += __shfl_xor(vl, msk, 64);
            vr += __shfl_xor(vr, msk, 64);
        }
        if (col == 0 && r < n) { el[r] = vl; er[r] = vr; }
    }
}

// Fused fine-sort + aggregation. One block per coarse bucket (64 dsts).
// Stage edges to LDS, 64-bin fine CSR in LDS, then wave wv aggregates dsts
// [wv*16, wv*16+16): online softmax + z-row gather (exs broadcast from LDS).
__global__ __launch_bounds__(256) void k_fagg(
        const uint32_t* __restrict__ binned, const int* __restrict__ bbase,
        const int* __restrict__ total,
        const _Float16* __restrict__ z, const float* __restrict__ el,
        const float* __restrict__ er, float* __restrict__ out, int n)
{
    __shared__ uint32_t pr[CAPE];       // 16 KB staged (dst<<16|src) pairs
    __shared__ uint16_t adjs[CAPE];     // 8 KB fine-sorted src ids
    __shared__ int fcnt[64], foff[64], fcur[64];
    __shared__ float exs[4][64];

    const int j   = blockIdx.x, tid = threadIdx.x;
    const int lane = tid & 63;
    const int wv   = tid >> 6;
    const int ebase = bbase[j];
    int ecnt = total[j]; if (ecnt > CAPE) ecnt = CAPE;   // unreachable for Poisson(1024)

    for (int i = tid; i < ecnt; i += 256) pr[i] = binned[ebase + i];
    if (tid < 64) { fcnt[tid] = 0; fcur[tid] = 0; }
    __syncthreads();
    for (int i = tid; i < ecnt; i += 256)
        atomicAdd(&fcnt[(pr[i] >> 16) & 63], 1);
    __syncthreads();
    if (tid < 64) {
        const int v = fcnt[tid];
        int incl = v;
        #pragma unroll
        for (int ofs = 1; ofs < 64; ofs <<= 1) {
            int u = __shfl_up(incl, ofs, 64);
            if (tid >= ofs) incl += u;
        }
        foff[tid] = incl - v;
    }
    __syncthreads();
    for (int i = tid; i < ecnt; i += 256) {
        const uint32_t u = pr[i];
        const int ld = (u >> 16) & 63;
        const int r = atomicAdd(&fcur[ld], 1);
        adjs[foff[ld] + r] = (uint16_t)(u & 0xFFFFu);
    }
    __syncthreads();

    // aggregation: wave wv handles 16 consecutive local dsts
    for (int ld = wv * 16; ld < wv * 16 + 16; ++ld) {
        const int d = j * 64 + ld;
        if (d >= n) continue;
        const int deg = fcnt[ld];
        const int sb  = foff[ld];
        const float erd = er[d];

        float m = -INFINITY, den = 0.f, acc = 0.f;
        for (int b0 = 0; b0 < deg; b0 += 64) {
            const int i = b0 + lane;
            float lgv = -INFINITY;
            if (i < deg) {
                const int s = adjs[sb + i];
                const float x = el[s] + erd;
                lgv = x > 0.f ? x : 0.01f * x;   // leaky_relu(0.01)
            }
            float cm = lgv;
            #pragma unroll
            for (int msk = 32; msk >= 1; msk >>= 1) cm = fmaxf(cm, __shfl_xor(cm, msk, 64));
            const float newm = fmaxf(m, cm);
            const float ex = (i < deg) ? __expf(lgv - newm) : 0.f;
            exs[wv][lane] = ex;                  // ex==0 pads invalid lanes
            float sum = ex;
            #pragma unroll
            for (int msk = 32; msk >= 1; msk >>= 1) sum += __shfl_xor(sum, msk, 64);
            const float scale = __expf(m - newm);    // first iter: exp(-inf)=0
            den = den * scale + sum;
            acc *= scale;
            m = newm;
            asm volatile("s_waitcnt lgkmcnt(0)" ::: "memory");

            const int cd = (deg - b0 < 64) ? deg - b0 : 64;
            #pragma unroll 8
            for (int q = 0; q < cd; ++q) {
                const float wq = exs[wv][q];             // wave-uniform broadcast
                const int   sq = adjs[sb + b0 + q];      // wave-uniform broadcast
                acc = fmaf(wq, (float)z[(size_t)sq * OUT_D + lane], acc);
            }
        }
        const float h = (deg > 0) ? acc / den : 0.f;
        out[(size_t)d * OUT_D + lane] = h > 0.f ? h : expm1f(h);  // elu
    }
}

extern "C" void kernel_launch(void* const* d_in, const int* in_sizes, int n_in,
                              void* d_out, int out_size, void* d_ws, size_t ws_size,
                              hipStream_t stream) {
    const float* feat = (const float*)d_in[0];
    const float* W    = (const float*)d_in[1];
    const float* a    = (const float*)d_in[2];
    const int*   src  = (const int*)d_in[3];
    const int*   dst  = (const int*)d_in[4];
    const int n = in_sizes[0] / IN_D;
    const int E = in_sizes[3];
    float* out = (float*)d_out;

    const int nb = (n + 63) >> 6;                          // coarse buckets
    const int chunk = (((E + NBLK - 1) / NBLK) + 3) & ~3;  // multiple of 4

    // ws: z_h | el | er | total | bbase | cursor | blkcnt | binned | Wf
    char* ws = (char*)d_ws;
    _Float16* z_h = (_Float16*)ws;    ws += (size_t)n * OUT_D * 2;
    float* el = (float*)ws;           ws += (size_t)n * 4;
    float* er = (float*)ws;           ws += (size_t)n * 4;
    int*  total = (int*)ws;           ws += (size_t)NBMAX * 4;
    int*  bbase = (int*)ws;           ws += (size_t)NBMAX * 4;
    int*  cursor = (int*)ws;          ws += 16;
    int*  blkcnt = (int*)ws;          ws += (size_t)NBLK * NBMAX * 4;
    uint32_t* binned = (uint32_t*)ws; ws += (size_t)E * 4;
    _Float16* Wf = (_Float16*)ws;

    k_count<<<NBLK, 256, 0, stream>>>(dst, blkcnt, cursor, E, nb, chunk);
    k_bsum<<<(nb + 255) / 256, 256, 0, stream>>>(blkcnt, total, bbase, cursor, nb);
    k_bin<<<NBLK, 256, 0, stream>>>(dst, src, blkcnt, bbase, binned, E, nb, chunk);
    k_wconv<<<IN_D * OUT_D / 256, 256, 0, stream>>>(W, Wf);
    k_gemmf16<<<(n + 63) / 64, 256, 0, stream>>>(feat, Wf, a, z_h, el, er, n);
    k_fagg<<<nb, 256, 0, stream>>>(binned, bbase, total, z_h, el, er, out, n);
}

// Round 8
// 165.829 us; speedup vs baseline: 1.1051x; 1.1051x over previous
//
#include <hip/hip_runtime.h>
#include <math.h>
#include <stdint.h>

// Single-head GAT layer, MI355X (gfx950). 6 kernels:
//   k_count : per-block LDS histogram over coarse buckets (dst>>6); zeroes cursor
//   k_bsum  : per-bucket totals across blocks + order-free base alloc
//             (wave shfl-scan + one atomicAdd per wave)
//   k_bin   : re-read edges, LDS cursors -> packed (dst<<16|src) per bucket
//   k_wconv : W f32[256][64] -> f16 B-fragment-ordered Wf (32KB)
//   k_gemmf16: z = X@W via mfma_f32_16x16x32_f16, fused el/er; z stored f16
//   k_fagg  : per bucket (1024 thr / 16 waves): stage edges->LDS, fine 64-bin
//             CSR in LDS, then 4 dsts per wave: online softmax + z gather

constexpr int IN_D   = 256;
constexpr int OUT_D  = 64;
constexpr int NBLK   = 256;    // binning blocks
constexpr int NBMAX  = 1024;   // max coarse buckets (n <= 65536)
constexpr int CAPE   = 4096;   // max edges per coarse bucket (mean ~1024)
constexpr int FWAVES = 16;     // waves per fagg block

typedef _Float16 f16x8 __attribute__((ext_vector_type(8)));
typedef float    f32x4 __attribute__((ext_vector_type(4)));

__device__ __forceinline__ void gload_lds16(const void* g, void* l) {
    __builtin_amdgcn_global_load_lds(
        (const __attribute__((address_space(1))) uint32_t*)g,
        (__attribute__((address_space(3))) uint32_t*)l, 16, 0, 0);
}

// ---- build phase ----

__global__ __launch_bounds__(256) void k_count(const int* __restrict__ dst,
                                               int* __restrict__ blkcnt,
                                               int* __restrict__ cursor,
                                               int E, int nb, int chunk) {
    __shared__ int cnt[NBMAX];
    const int b = blockIdx.x, tid = threadIdx.x;
    if (b == 0 && tid == 0) *cursor = 0;
    for (int i = tid; i < nb; i += 256) cnt[i] = 0;
    __syncthreads();
    const int lo = b * chunk;
    const int hi = (lo + chunk < E) ? lo + chunk : E;
    const int nv = (hi - lo) & ~3;
    for (int e = lo + tid * 4; e < lo + nv; e += 1024) {
        int4 d4 = *(const int4*)&dst[e];
        atomicAdd(&cnt[d4.x >> 6], 1);
        atomicAdd(&cnt[d4.y >> 6], 1);
        atomicAdd(&cnt[d4.z >> 6], 1);
        atomicAdd(&cnt[d4.w >> 6], 1);
    }
    for (int e = lo + nv + tid; e < hi; e += 256) atomicAdd(&cnt[dst[e] >> 6], 1);
    __syncthreads();
    for (int i = tid; i < nb; i += 256) blkcnt[(size_t)b * NBMAX + i] = cnt[i];
}

// Per-bucket prefix over blocks + contiguous base allocation (order-free).
__global__ __launch_bounds__(256) void k_bsum(int* __restrict__ blkcnt,
                                              int* __restrict__ total,
                                              int* __restrict__ bbase,
                                              int* __restrict__ cursor, int nb) {
    const int j = blockIdx.x * 256 + threadIdx.x;
    const int lane = threadIdx.x & 63;
    int run = 0;
    if (j < nb) {
        #pragma unroll 8
        for (int b = 0; b < NBLK; ++b) {
            int v = blkcnt[(size_t)b * NBMAX + j];
            blkcnt[(size_t)b * NBMAX + j] = run;   // prefix of blocks < b
            run += v;
        }
    }
    int incl = run;
    #pragma unroll
    for (int ofs = 1; ofs < 64; ofs <<= 1) {
        int u = __shfl_up(incl, ofs, 64);
        if (lane >= ofs) incl += u;
    }
    int base = 0;
    if (lane == 63) base = atomicAdd(cursor, incl);   // wave total
    base = __shfl(base, 63, 64);
    if (j < nb) { total[j] = run; bbase[j] = base + incl - run; }
}

__global__ __launch_bounds__(256) void k_bin(const int* __restrict__ dst,
                                             const int* __restrict__ src,
                                             const int* __restrict__ blkcnt,
                                             const int* __restrict__ bbase,
                                             uint32_t* __restrict__ binned,
                                             int E, int nb, int chunk) {
    __shared__ int cur[NBMAX];
    const int b = blockIdx.x, tid = threadIdx.x;
    for (int i = tid; i < nb; i += 256)
        cur[i] = bbase[i] + blkcnt[(size_t)b * NBMAX + i];
    __syncthreads();
    const int lo = b * chunk;
    const int hi = (lo + chunk < E) ? lo + chunk : E;
    const int nv = (hi - lo) & ~3;
    for (int e = lo + tid * 4; e < lo + nv; e += 1024) {
        int4 d4 = *(const int4*)&dst[e];
        int4 s4 = *(const int4*)&src[e];
        int p;
        p = atomicAdd(&cur[d4.x >> 6], 1); binned[p] = ((uint32_t)d4.x << 16) | (uint32_t)s4.x;
        p = atomicAdd(&cur[d4.y >> 6], 1); binned[p] = ((uint32_t)d4.y << 16) | (uint32_t)s4.y;
        p = atomicAdd(&cur[d4.z >> 6], 1); binned[p] = ((uint32_t)d4.z << 16) | (uint32_t)s4.z;
        p = atomicAdd(&cur[d4.w >> 6], 1); binned[p] = ((uint32_t)d4.w << 16) | (uint32_t)s4.w;
    }
    for (int e = lo + nv + tid; e < hi; e += 256) {
        const uint32_t d = (uint32_t)dst[e];
        const int pos = atomicAdd(&cur[d >> 6], 1);
        binned[pos] = (d << 16) | (uint32_t)src[e];
    }
}

// ---- math phase ----

// Wf[t], t = ((kc*4+ct)*64+lane)*8+j  holds W[kc*32+(lane>>4)*8+j][ct*16+(lane&15)]
__global__ void k_wconv(const float* __restrict__ W, _Float16* __restrict__ Wf) {
    int t = blockIdx.x * 256 + threadIdx.x;          // 16384 total
    int j    = t & 7;
    int lane = (t >> 3) & 63;
    int ct   = (t >> 9) & 3;
    int kc   = t >> 11;
    int k = kc * 32 + (lane >> 4) * 8 + j;
    int c = ct * 16 + (lane & 15);
    Wf[t] = (_Float16)W[k * OUT_D + c];
}

// Block: 256 thr / 4 waves; wave: 16 rows x 64 cols, K=256 in 8 chunks.
// C/D layout (m89): col = lane&15, row = (lane>>4)*4 + reg.
__global__ __launch_bounds__(256) void k_gemmf16(
        const float* __restrict__ feat, const _Float16* __restrict__ Wf,
        const float* __restrict__ a,
        _Float16* __restrict__ z, float* __restrict__ el, float* __restrict__ er,
        int n)
{
    __shared__ __align__(16) _Float16 WfL[IN_D * OUT_D];   // 32 KB, frag order

    const int tid  = threadIdx.x;
    const int lane = tid & 63;
    const int wv   = tid >> 6;
    const int row0 = blockIdx.x * 64 + wv * 16;
    const int kg   = lane >> 4;

    int gr = row0 + (lane & 15); if (gr > n - 1) gr = n - 1;
    const float* frow = feat + (size_t)gr * IN_D;
    float4 r0[8], r1[8];
    #pragma unroll
    for (int kc = 0; kc < 8; ++kc) {
        const float4* fp = (const float4*)(frow + kc * 32 + kg * 8);
        r0[kc] = fp[0];
        r1[kc] = fp[1];
    }

    #pragma unroll
    for (int i = 0; i < 8; ++i) {
        const char* gsrc = (const char*)Wf + (size_t)(i * 256 + tid) * 16;
        char* ldst = (char*)WfL + (size_t)(i * 256 + wv * 64) * 16;
        gload_lds16(gsrc, ldst);
    }
    __syncthreads();

    f32x4 acc[4];
    #pragma unroll
    for (int ct = 0; ct < 4; ++ct) acc[ct] = (f32x4){0.f, 0.f, 0.f, 0.f};

    #pragma unroll
    for (int kc = 0; kc < 8; ++kc) {
        f16x8 af;
        af[0] = (_Float16)r0[kc].x; af[1] = (_Float16)r0[kc].y;
        af[2] = (_Float16)r0[kc].z; af[3] = (_Float16)r0[kc].w;
        af[4] = (_Float16)r1[kc].x; af[5] = (_Float16)r1[kc].y;
        af[6] = (_Float16)r1[kc].z; af[7] = (_Float16)r1[kc].w;
        #pragma unroll
        for (int ct = 0; ct < 4; ++ct) {
            f16x8 bf = *(const f16x8*)&WfL[((kc * 4 + ct) * 64 + lane) * 8];
            acc[ct] = __builtin_amdgcn_mfma_f32_16x16x32_f16(af, bf, acc[ct], 0, 0, 0);
        }
    }

    const int col = lane & 15;
    float av[4], bv[4];
    #pragma unroll
    for (int ct = 0; ct < 4; ++ct) {
        av[ct] = a[ct * 16 + col];
        bv[ct] = a[OUT_D + ct * 16 + col];
    }
    #pragma unroll
    for (int i = 0; i < 4; ++i) {
        const int r = row0 + (lane >> 4) * 4 + i;
        float vl = 0.f, vr = 0.f;
        #pragma unroll
        for (int ct = 0; ct < 4; ++ct) {
            float zv = acc[ct][i];
            if (r < n) z[(size_t)r * OUT_D + ct * 16 + col] = (_Float16)zv;
            vl = fmaf(zv, av[ct], vl);
            vr = fmaf(zv, bv[ct], vr);
        }
        #pragma unroll
        for (int msk = 8; msk >= 1; msk >>= 1) {
            vl += __shfl_xor(vl, msk, 64);
            vr += __shfl_xor(vr, msk, 64);
        }
        if (col == 0 && r < n) { el[r] = vl; er[r] = vr; }
    }
}

// Fused fine-sort + aggregation. One 1024-thread block per coarse bucket.
// Build: stage edges to LDS, 64-bin fine CSR in LDS (no global adj).
// Aggregate: wave wv handles dsts {wv*4 .. wv*4+3}: online softmax + gather.
__global__ __launch_bounds__(1024) void k_fagg(
        const uint32_t* __restrict__ binned, const int* __restrict__ bbase,
        const int* __restrict__ total,
        const _Float16* __restrict__ z, const float* __restrict__ el,
        const float* __restrict__ er, float* __restrict__ out, int n)
{
    __shared__ uint32_t pr[CAPE];       // 16 KB staged (dst<<16|src) pairs
    __shared__ uint16_t adjs[CAPE];     // 8 KB fine-sorted src ids
    __shared__ int fcnt[64], foff[64], fcur[64];
    __shared__ float exs[FWAVES][64];   // 4 KB

    const int j   = blockIdx.x, tid = threadIdx.x;
    const int lane = tid & 63;
    const int wv   = tid >> 6;
    const int ebase = bbase[j];
    int ecnt = total[j]; if (ecnt > CAPE) ecnt = CAPE;   // unreachable for Poisson

    for (int i = tid; i < ecnt; i += 1024) pr[i] = binned[ebase + i];
    if (tid < 64) { fcnt[tid] = 0; fcur[tid] = 0; }
    __syncthreads();
    for (int i = tid; i < ecnt; i += 1024)
        atomicAdd(&fcnt[(pr[i] >> 16) & 63], 1);
    __syncthreads();
    if (tid < 64) {
        const int v = fcnt[tid];
        int incl = v;
        #pragma unroll
        for (int ofs = 1; ofs < 64; ofs <<= 1) {
            int u = __shfl_up(incl, ofs, 64);
            if (tid >= ofs) incl += u;
        }
        foff[tid] = incl - v;
    }
    __syncthreads();
    for (int i = tid; i < ecnt; i += 1024) {
        const uint32_t u = pr[i];
        const int ld = (u >> 16) & 63;
        const int r = atomicAdd(&fcur[ld], 1);
        adjs[foff[ld] + r] = (uint16_t)(u & 0xFFFFu);
    }
    __syncthreads();

    // aggregation: wave wv handles 4 consecutive local dsts
    #pragma unroll
    for (int t = 0; t < 64 / FWAVES; ++t) {
        const int ld = wv * (64 / FWAVES) + t;
        const int d = j * 64 + ld;
        if (d >= n) continue;              // wave-uniform
        const int deg = fcnt[ld];
        const int sb  = foff[ld];
        const float erd = er[d];

        float m = -INFINITY, den = 0.f, acc = 0.f;
        for (int b0 = 0; b0 < deg; b0 += 64) {
            const int i = b0 + lane;
            float lgv = -INFINITY;
            if (i < deg) {
                const int s = adjs[sb + i];
                const float x = el[s] + erd;
                lgv = x > 0.f ? x : 0.01f * x;   // leaky_relu(0.01)
            }
            float cm = lgv;
            #pragma unroll
            for (int msk = 32; msk >= 1; msk >>= 1) cm = fmaxf(cm, __shfl_xor(cm, msk, 64));
            const float newm = fmaxf(m, cm);
            const float ex = (i < deg) ? __expf(lgv - newm) : 0.f;
            exs[wv][lane] = ex;                  // ex==0 pads invalid lanes
            float sum = ex;
            #pragma unroll
            for (int msk = 32; msk >= 1; msk >>= 1) sum += __shfl_xor(sum, msk, 64);
            const float scale = __expf(m - newm);    // first iter: exp(-inf)=0
            den = den * scale + sum;
            acc *= scale;
            m = newm;
            asm volatile("s_waitcnt lgkmcnt(0)" ::: "memory");

            const int cd = (deg - b0 < 64) ? deg - b0 : 64;
            #pragma unroll 8
            for (int q = 0; q < cd; ++q) {
                const float wq = exs[wv][q];             // wave-uniform broadcast
                const int   sq = adjs[sb + b0 + q];      // wave-uniform broadcast
                acc = fmaf(wq, (float)z[(size_t)sq * OUT_D + lane], acc);
            }
        }
        const float h = (deg > 0) ? acc / den : 0.f;
        out[(size_t)d * OUT_D + lane] = h > 0.f ? h : expm1f(h);  // elu
    }
}

extern "C" void kernel_launch(void* const* d_in, const int* in_sizes, int n_in,
                              void* d_out, int out_size, void* d_ws, size_t ws_size,
                              hipStream_t stream) {
    const float* feat = (const float*)d_in[0];
    const float* W    = (const float*)d_in[1];
    const float* a    = (const float*)d_in[2];
    const int*   src  = (const int*)d_in[3];
    const int*   dst  = (const int*)d_in[4];
    const int n = in_sizes[0] / IN_D;
    const int E = in_sizes[3];
    float* out = (float*)d_out;

    const int nb = (n + 63) >> 6;                          // coarse buckets
    const int chunk = (((E + NBLK - 1) / NBLK) + 3) & ~3;  // multiple of 4

    // ws: z_h | el | er | total | bbase | cursor | blkcnt | binned | Wf
    char* ws = (char*)d_ws;
    _Float16* z_h = (_Float16*)ws;    ws += (size_t)n * OUT_D * 2;
    float* el = (float*)ws;           ws += (size_t)n * 4;
    float* er = (float*)ws;           ws += (size_t)n * 4;
    int*  total = (int*)ws;           ws += (size_t)NBMAX * 4;
    int*  bbase = (int*)ws;           ws += (size_t)NBMAX * 4;
    int*  cursor = (int*)ws;          ws += 16;
    int*  blkcnt = (int*)ws;          ws += (size_t)NBLK * NBMAX * 4;
    uint32_t* binned = (uint32_t*)ws; ws += (size_t)E * 4;
    _Float16* Wf = (_Float16*)ws;

    k_count<<<NBLK, 256, 0, stream>>>(dst, blkcnt, cursor, E, nb, chunk);
    k_bsum<<<(nb + 255) / 256, 256, 0, stream>>>(blkcnt, total, bbase, cursor, nb);
    k_bin<<<NBLK, 256, 0, stream>>>(dst, src, blkcnt, bbase, binned, E, nb, chunk);
    k_wconv<<<IN_D * OUT_D / 256, 256, 0, stream>>>(W, Wf);
    k_gemmf16<<<(n + 63) / 64, 256, 0, stream>>>(feat, Wf, a, z_h, el, er, n);
    k_fagg<<<nb, 1024, 0, stream>>>(binned, bbase, total, z_h, el, er, out, n);
}